// Round 6
// baseline (184.642 us; speedup 1.0000x reference)
//
#include <hip/hip_runtime.h>
#include <hip/hip_bf16.h>

typedef unsigned short ushort_t;
typedef __attribute__((ext_vector_type(8))) short short8;
typedef __attribute__((ext_vector_type(4))) float floatx4;

// B=512, S=64, N=8, D=64, A=16, H=256, IN_DIM=640

__device__ __forceinline__ float mish_f(float x) {
    float e = __expf(x);
    float w = fmaf(e, e + 2.0f, 2.0f);   // e^2x + 2e^x + 2, >= 2
    return x - 2.0f * x * __builtin_amdgcn_rcpf(w);
}

__device__ __forceinline__ unsigned f2bf_u(float f) {
    unsigned int u = __float_as_uint(f);
    return (u + 0x7fffu + ((u >> 16) & 1u)) >> 16;  // RNE
}

__device__ __forceinline__ unsigned pk_bf2(float a, float b) {
    return f2bf_u(a) | (f2bf_u(b) << 16);
}

// ---------------- prep ----------------
// blocks [0,512):     obsW[b][t] = state[b]@W1obs + b1  (fp32)
// blocks [512,4608):  actW bf16, one block per (b = idx>>3, j = idx&7)
// blocks [4608,4672): W2T bf16 transpose
__global__ __launch_bounds__(256) void prep_kernel(
        const float* __restrict__ state,
        const float* __restrict__ action,
        const float* __restrict__ W1,
        const float* __restrict__ b1,
        const float* __restrict__ W2,
        float* __restrict__ obsW,
        ushort_t* __restrict__ actW,
        ushort_t* __restrict__ W2T) {
    int bid = blockIdx.x;
    int t = threadIdx.x;
    if (bid < 512) {
        int b = bid;
        const float* stp = state + (size_t)b * 512;   // wave-uniform -> s_load
        const float* w1p = W1 + t;
        float a0 = 0.f, a1 = 0.f, a2 = 0.f, a3 = 0.f;
#pragma unroll 8
        for (int f = 0; f < 512; f += 4) {
            a0 = fmaf(stp[f + 0], w1p[(f + 0) * 256], a0);
            a1 = fmaf(stp[f + 1], w1p[(f + 1) * 256], a1);
            a2 = fmaf(stp[f + 2], w1p[(f + 2) * 256], a2);
            a3 = fmaf(stp[f + 3], w1p[(f + 3) * 256], a3);
        }
        obsW[b * 256 + t] = (a0 + a1) + (a2 + a3) + b1[t];
    } else if (bid < 4608) {
        int idx = bid - 512;
        int b = idx >> 3;
        int j = idx & 7;
        const float* acp = action + (size_t)b * 128;  // wave-uniform -> s_load
        const float* W1a = W1 + (size_t)(512 + j * 16) * 256;
        float acc[8];
#pragma unroll
        for (int n = 0; n < 8; ++n) acc[n] = 0.f;
#pragma unroll
        for (int a = 0; a < 16; ++a) {
            float w = W1a[a * 256 + t];
#pragma unroll
            for (int n = 0; n < 8; ++n)
                acc[n] = fmaf(acp[n * 16 + a], w, acc[n]);
        }
#pragma unroll
        for (int n = 0; n < 8; ++n)
            actW[(((size_t)b * 8 + n) * 8 + j) * 256 + t] = (ushort_t)f2bf_u(acc[n]);
    } else {
        int n = (bid - 4608) * 4 + (t >> 6);
        int klo = (t & 63);
        for (int kk = 0; kk < 4; ++kk) {
            int k = kk * 64 + klo;
            W2T[n * 256 + k] = (ushort_t)f2bf_u(W2[k * 256 + n]);
        }
    }
}

// ---------------- main: h1 build (frag-order LDS) + layer2 MFMA + layer3 + reduce ----------------
// h1 layout: chunk (mt,ks) of 1056B (528 ushorts = 1KB data + 32B pad);
// within chunk, lane L=(q*16+lo) holds granule (ks*4+q) of row (mt*16+lo) at L*16B.
#define CHUNK_US 528   // ushorts per chunk

__global__ __launch_bounds__(512, 4) void main_kernel(
        const float* __restrict__ obsW, const ushort_t* __restrict__ actW,
        const ushort_t* __restrict__ W2T, const int* __restrict__ perm,
        const float* __restrict__ b2,
        const float* __restrict__ W3, const float* __restrict__ b3,
        float* __restrict__ out) {
    __shared__ __align__(16) ushort_t h1[32 * CHUNK_US];   // 33 KB
    __shared__ __align__(16) float obsb[256];
    __shared__ int perm_s[64];
    __shared__ float qpart[8][64];
    __shared__ float qv_s[64];

    int t = threadIdx.x;
    int bid = blockIdx.x;
    // XCD swizzle: all 8 s-group blocks of one b share blockIdx%8 -> same XCD L2
    int b = (bid & 7) * 64 + ((bid >> 3) & 63);
    int sg = bid >> 9;
    int s0 = sg * 8;

    int w = t >> 6;        // wave 0..7
    int L = t & 63;
    int lo = L & 15;
    int q = L >> 4;

    if (t < 256) obsb[t] = obsW[b * 256 + t];            // includes b1
    else if (t < 320) perm_s[t - 256] = perm[((size_t)b * 64 + s0) * 8 + (t - 256)];

    // hoist first 4 B-operand loads (independent of LDS)
    const ushort_t* w2base = W2T + ((size_t)(w * 32 + lo)) * 256 + q * 8;
    short8 bpre[4];
    bpre[0] = *reinterpret_cast<const short8*>(w2base + 0 * 16 * 256 + 0 * 32);
    bpre[1] = *reinterpret_cast<const short8*>(w2base + 1 * 16 * 256 + 0 * 32);
    bpre[2] = *reinterpret_cast<const short8*>(w2base + 0 * 16 * 256 + 1 * 32);
    bpre[3] = *reinterpret_cast<const short8*>(w2base + 1 * 16 * 256 + 1 * 32);

    __syncthreads();

    // ---- build h1: thread = (sl = wave, half-granule hg = lane); 4 cols/thread ----
    {
        int sl = w;                  // s-slot 0..7
        int hg = L;                  // half-granule 0..63 -> cols hg*4..hg*4+3
        int g = hg >> 1;
        int ks = g >> 2;
        int qq = g & 3;
        int half = hg & 1;
        const ushort_t* actg = actW + (size_t)b * 64 * 256 + hg * 4;
        uint2 av[8];
#pragma unroll
        for (int j = 0; j < 8; ++j) {
            int p = perm_s[sl * 8 + j];
            av[j] = *reinterpret_cast<const uint2*>(actg + (p * 8 + j) * 256);
        }
        float4 ob = *reinterpret_cast<const float4*>(obsb + hg * 4);
        float r0 = ob.x, r1 = ob.y, r2 = ob.z, r3 = ob.w;
        ushort_t* dst0 = h1 + (qq * 16) * 8 + half * 4 + ks * CHUNK_US;
#pragma unroll
        for (int j = 0; j < 8; ++j) {
            r0 += __uint_as_float(av[j].x << 16);
            r1 += __uint_as_float(av[j].x & 0xffff0000u);
            r2 += __uint_as_float(av[j].y << 16);
            r3 += __uint_as_float(av[j].y & 0xffff0000u);
            int row = sl * 8 + j;
            int mt = row >> 4, lr = row & 15;
            uint2 pk = make_uint2(pk_bf2(mish_f(r0), mish_f(r1)),
                                  pk_bf2(mish_f(r2), mish_f(r3)));
            *reinterpret_cast<uint2*>(dst0 + mt * 8 * CHUNK_US + lr * 8) = pk;
        }
    }
    __syncthreads();

    // ---- layer2: M=64, N=256, K=256; wave w owns 32-col N-strip ----
    floatx4 acc[4][2];
#pragma unroll
    for (int mt = 0; mt < 4; ++mt)
#pragma unroll
        for (int nt = 0; nt < 2; ++nt)
            acc[mt][nt] = (floatx4){0.f, 0.f, 0.f, 0.f};

    const ushort_t* h1b = h1 + L * 8;   // lane offset L*16B

#pragma unroll
    for (int ks = 0; ks < 8; ++ks) {
        short8 afr[4];
#pragma unroll
        for (int mt = 0; mt < 4; ++mt)
            afr[mt] = *reinterpret_cast<const short8*>(h1b + (mt * 8 + ks) * CHUNK_US);
#pragma unroll
        for (int nt = 0; nt < 2; ++nt) {
            short8 bfr;
            if (ks == 0)      bfr = bpre[nt];
            else if (ks == 1) bfr = bpre[2 + nt];
            else              bfr = *reinterpret_cast<const short8*>(w2base + nt * 16 * 256 + ks * 32);
#pragma unroll
            for (int mt = 0; mt < 4; ++mt)
                acc[mt][nt] = __builtin_amdgcn_mfma_f32_16x16x32_bf16(afr[mt], bfr, acc[mt][nt], 0, 0, 0);
        }
    }

    // ---- epilogue: h2 = mish(acc + b2), layer3 partial dot with W3 ----
    float b2c[2], w3c[2];
#pragma unroll
    for (int nt = 0; nt < 2; ++nt) {
        int col = w * 32 + nt * 16 + lo;
        b2c[nt] = b2[col];
        w3c[nt] = W3[col];
    }
#pragma unroll
    for (int mt = 0; mt < 4; ++mt) {
        float part[4] = {0.f, 0.f, 0.f, 0.f};
#pragma unroll
        for (int nt = 0; nt < 2; ++nt) {
#pragma unroll
            for (int r = 0; r < 4; ++r) {
                float h2 = mish_f(acc[mt][nt][r] + b2c[nt]);
                part[r] = fmaf(h2, w3c[nt], part[r]);
            }
        }
#pragma unroll
        for (int r = 0; r < 4; ++r) {
            float v = part[r];
            v += __shfl_xor(v, 1);
            v += __shfl_xor(v, 2);
            v += __shfl_xor(v, 4);
            v += __shfl_xor(v, 8);
            if (lo == 0) qpart[w][mt * 16 + q * 4 + r] = v;
        }
    }
    __syncthreads();
    if (t < 64) {
        float qv = b3[0];
#pragma unroll
        for (int ww = 0; ww < 8; ++ww) qv += qpart[ww][t];
        qv_s[t] = qv;    // row t = sl*8 + k
    }
    __syncthreads();
    // fused final: partial over this block's 8 s-values, atomic into out
    if (t < 8) {
        float p = 0.f;
#pragma unroll
        for (int sl = 0; sl < 8; ++sl)
            p += qv_s[sl * 8 + perm_s[sl * 8 + t]];
        p *= (1.0f / 64.0f);
        atomicAdd(&out[b * 8 + t], p);
        atomicAdd(&out[4096 + b * 8 + t], p);
    }
}

extern "C" void kernel_launch(void* const* d_in, const int* in_sizes, int n_in,
                              void* d_out, int out_size, void* d_ws, size_t ws_size,
                              hipStream_t stream) {
    const float* state  = (const float*)d_in[0];
    const float* action = (const float*)d_in[1];
    const float* W1     = (const float*)d_in[2];
    const float* b1     = (const float*)d_in[3];
    const float* W2     = (const float*)d_in[4];
    const float* b2     = (const float*)d_in[5];
    const float* W3     = (const float*)d_in[6];
    const float* b3     = (const float*)d_in[7];
    const int*   perm   = (const int*)d_in[8];
    float* out = (float*)d_out;

    char* ws = (char*)d_ws;
    float*    obsW = (float*)ws;                          // 512*256*4    = 0.5 MB
    ushort_t* actW = (ushort_t*)(ws + 524288);            // 512*64*256*2 = 16 MB
    ushort_t* W2T  = (ushort_t*)(ws + 524288 + 16777216); // 128 KB

    (void)hipMemsetAsync(out, 0, (size_t)out_size * sizeof(float), stream);
    prep_kernel<<<4672, 256, 0, stream>>>(state, action, W1, b1, W2, obsW, actW, W2T);
    main_kernel<<<4096, 512, 0, stream>>>(obsW, actW, W2T, perm, b2, W3, b3, out);
}

// Round 7
// 184.440 us; speedup vs baseline: 1.0011x; 1.0011x over previous
//
#include <hip/hip_runtime.h>
#include <hip/hip_bf16.h>

typedef unsigned short ushort_t;
typedef __attribute__((ext_vector_type(8))) short short8;
typedef __attribute__((ext_vector_type(4))) float floatx4;

// B=512, S=64, N=8, D=64, A=16, H=256, IN_DIM=640

__device__ __forceinline__ float mish_f(float x) {
    float e = __expf(x);
    float w = fmaf(e, e + 2.0f, 2.0f);   // e^2x + 2e^x + 2, >= 2
    return x - 2.0f * x * __builtin_amdgcn_rcpf(w);
}

// round-half-up bf16 (ties differ from RNE by 1 ulp; threshold slack 4.6x)
__device__ __forceinline__ unsigned f2bf_u(float f) {
    return (__float_as_uint(f) + 0x8000u) >> 16;
}

// pack two floats to bf16x2 in 3 VALU: add, add, v_perm
__device__ __forceinline__ unsigned pk_bf2(float a, float b) {
    unsigned ua = __float_as_uint(a) + 0x8000u;
    unsigned ub = __float_as_uint(b) + 0x8000u;
#if __has_builtin(__builtin_amdgcn_perm)
    // D.b0=ua.b2, D.b1=ua.b3 (low16=bf16(a)); D.b2=ub.b2, D.b3=ub.b3
    return __builtin_amdgcn_perm(ua, ub, 0x03020706u);
#else
    return (ua >> 16) | (ub & 0xffff0000u);
#endif
}

// ---------------- prep ----------------
// blocks [0,512):      obsW[b][t] = state[b]@W1obs + b1  (fp32)
// blocks [512,1536):   actW bf16: idx=bid-512, j=idx&7, b0=(idx>>3)*4 (4 b per block)
// blocks [1536,1600):  W2T bf16 transpose
__global__ __launch_bounds__(256) void prep_kernel(
        const float* __restrict__ state,
        const float* __restrict__ action,
        const float* __restrict__ W1,
        const float* __restrict__ b1,
        const float* __restrict__ W2,
        float* __restrict__ obsW,
        ushort_t* __restrict__ actW,
        ushort_t* __restrict__ W2T) {
    int bid = blockIdx.x;
    int t = threadIdx.x;
    if (bid < 512) {
        int b = bid;
        const float* stp = state + (size_t)b * 512;   // wave-uniform -> s_load
        const float* w1p = W1 + t;
        float a0 = 0.f, a1 = 0.f, a2 = 0.f, a3 = 0.f;
#pragma unroll 8
        for (int f = 0; f < 512; f += 4) {
            a0 = fmaf(stp[f + 0], w1p[(f + 0) * 256], a0);
            a1 = fmaf(stp[f + 1], w1p[(f + 1) * 256], a1);
            a2 = fmaf(stp[f + 2], w1p[(f + 2) * 256], a2);
            a3 = fmaf(stp[f + 3], w1p[(f + 3) * 256], a3);
        }
        obsW[b * 256 + t] = (a0 + a1) + (a2 + a3) + b1[t];
    } else if (bid < 1536) {
        int idx = bid - 512;
        int j = idx & 7;
        int b0 = (idx >> 3) * 4;
        const float* W1a = W1 + (size_t)(512 + j * 16) * 256;
        float wv[16];
#pragma unroll
        for (int a = 0; a < 16; ++a) wv[a] = W1a[a * 256 + t];
#pragma unroll
        for (int bb = 0; bb < 4; ++bb) {
            int b = b0 + bb;
            const float* acp = action + (size_t)b * 128;   // wave-uniform -> s_load
            float acc[8];
#pragma unroll
            for (int n = 0; n < 8; ++n) acc[n] = 0.f;
#pragma unroll
            for (int a = 0; a < 16; ++a) {
#pragma unroll
                for (int n = 0; n < 8; ++n)
                    acc[n] = fmaf(acp[n * 16 + a], wv[a], acc[n]);
            }
#pragma unroll
            for (int n = 0; n < 8; ++n)
                actW[(((size_t)b * 8 + n) * 8 + j) * 256 + t] = (ushort_t)f2bf_u(acc[n]);
        }
    } else {
        int n = (bid - 1536) * 4 + (t >> 6);
        int klo = (t & 63);
        for (int kk = 0; kk < 4; ++kk) {
            int k = kk * 64 + klo;
            W2T[n * 256 + k] = (ushort_t)f2bf_u(W2[k * 256 + n]);
        }
    }
}

// ---------------- main: h1 build (frag-order LDS) + layer2 MFMA + layer3 + reduce ----------------
// h1 layout: chunk (mt,ks) of 1056B (528 ushorts = 1KB data + 32B pad);
// within chunk, lane L=(q*16+lo) holds granule (ks*4+q) of row (mt*16+lo) at L*16B.
#define CHUNK_US 528   // ushorts per chunk

__global__ __launch_bounds__(512, 4) void main_kernel(
        const float* __restrict__ obsW, const ushort_t* __restrict__ actW,
        const ushort_t* __restrict__ W2T, const int* __restrict__ perm,
        const float* __restrict__ b2,
        const float* __restrict__ W3, const float* __restrict__ b3,
        float* __restrict__ out) {
    __shared__ __align__(16) ushort_t h1[32 * CHUNK_US];   // 33 KB
    __shared__ __align__(16) float obsb[256];
    __shared__ int perm_s[64];
    __shared__ float qpart[8][64];
    __shared__ float qv_s[64];

    int t = threadIdx.x;
    int bid = blockIdx.x;
    // XCD swizzle: all 8 s-group blocks of one b share blockIdx%8 -> same XCD L2
    int b = (bid & 7) * 64 + ((bid >> 3) & 63);
    int sg = bid >> 9;
    int s0 = sg * 8;

    int w = t >> 6;        // wave 0..7
    int L = t & 63;
    int lo = L & 15;
    int q = L >> 4;

    if (t < 256) obsb[t] = obsW[b * 256 + t];            // includes b1
    else if (t < 320) perm_s[t - 256] = perm[((size_t)b * 64 + s0) * 8 + (t - 256)];

    // hoist first 4 B-operand loads (independent of LDS)
    const ushort_t* w2base = W2T + ((size_t)(w * 32 + lo)) * 256 + q * 8;
    short8 bpre[4];
    bpre[0] = *reinterpret_cast<const short8*>(w2base + 0 * 16 * 256 + 0 * 32);
    bpre[1] = *reinterpret_cast<const short8*>(w2base + 1 * 16 * 256 + 0 * 32);
    bpre[2] = *reinterpret_cast<const short8*>(w2base + 0 * 16 * 256 + 1 * 32);
    bpre[3] = *reinterpret_cast<const short8*>(w2base + 1 * 16 * 256 + 1 * 32);

    __syncthreads();

    // ---- build h1: thread = (sl = wave, half-granule hg = lane); 4 cols/thread ----
    {
        int sl = w;                  // s-slot 0..7
        int hg = L;                  // half-granule 0..63 -> cols hg*4..hg*4+3
        int g = hg >> 1;
        int ks = g >> 2;
        int qq = g & 3;
        int half = hg & 1;
        const ushort_t* actg = actW + (size_t)b * 64 * 256 + hg * 4;
        uint2 av[8];
#pragma unroll
        for (int j = 0; j < 8; ++j) {
            int p = perm_s[sl * 8 + j];
            av[j] = *reinterpret_cast<const uint2*>(actg + (p * 8 + j) * 256);
        }
        float4 ob = *reinterpret_cast<const float4*>(obsb + hg * 4);
        float r0 = ob.x, r1 = ob.y, r2 = ob.z, r3 = ob.w;
        ushort_t* dst0 = h1 + (qq * 16) * 8 + half * 4 + ks * CHUNK_US;
#pragma unroll
        for (int j = 0; j < 8; ++j) {
            r0 += __uint_as_float(av[j].x << 16);
            r1 += __uint_as_float(av[j].x & 0xffff0000u);
            r2 += __uint_as_float(av[j].y << 16);
            r3 += __uint_as_float(av[j].y & 0xffff0000u);
            int row = sl * 8 + j;
            int mt = row >> 4, lr = row & 15;
            uint2 pk = make_uint2(pk_bf2(mish_f(r0), mish_f(r1)),
                                  pk_bf2(mish_f(r2), mish_f(r3)));
            *reinterpret_cast<uint2*>(dst0 + mt * 8 * CHUNK_US + lr * 8) = pk;
        }
    }
    __syncthreads();

    // ---- layer2: M=64, N=256, K=256; wave w owns 32-col N-strip ----
    floatx4 acc[4][2];
#pragma unroll
    for (int mt = 0; mt < 4; ++mt)
#pragma unroll
        for (int nt = 0; nt < 2; ++nt)
            acc[mt][nt] = (floatx4){0.f, 0.f, 0.f, 0.f};

    const ushort_t* h1b = h1 + L * 8;   // lane offset L*16B

#pragma unroll
    for (int ks = 0; ks < 8; ++ks) {
        short8 afr[4];
#pragma unroll
        for (int mt = 0; mt < 4; ++mt)
            afr[mt] = *reinterpret_cast<const short8*>(h1b + (mt * 8 + ks) * CHUNK_US);
#pragma unroll
        for (int nt = 0; nt < 2; ++nt) {
            short8 bfr;
            if (ks == 0)      bfr = bpre[nt];
            else if (ks == 1) bfr = bpre[2 + nt];
            else              bfr = *reinterpret_cast<const short8*>(w2base + nt * 16 * 256 + ks * 32);
#pragma unroll
            for (int mt = 0; mt < 4; ++mt)
                acc[mt][nt] = __builtin_amdgcn_mfma_f32_16x16x32_bf16(afr[mt], bfr, acc[mt][nt], 0, 0, 0);
        }
    }

    // ---- epilogue: h2 = mish(acc + b2), layer3 partial dot with W3 ----
    float b2c[2], w3c[2];
#pragma unroll
    for (int nt = 0; nt < 2; ++nt) {
        int col = w * 32 + nt * 16 + lo;
        b2c[nt] = b2[col];
        w3c[nt] = W3[col];
    }
#pragma unroll
    for (int mt = 0; mt < 4; ++mt) {
        float part[4] = {0.f, 0.f, 0.f, 0.f};
#pragma unroll
        for (int nt = 0; nt < 2; ++nt) {
#pragma unroll
            for (int r = 0; r < 4; ++r) {
                float h2 = mish_f(acc[mt][nt][r] + b2c[nt]);
                part[r] = fmaf(h2, w3c[nt], part[r]);
            }
        }
#pragma unroll
        for (int r = 0; r < 4; ++r) {
            float v = part[r];
            v += __shfl_xor(v, 1);
            v += __shfl_xor(v, 2);
            v += __shfl_xor(v, 4);
            v += __shfl_xor(v, 8);
            if (lo == 0) qpart[w][mt * 16 + q * 4 + r] = v;
        }
    }
    __syncthreads();
    if (t < 64) {
        float qv = b3[0];
#pragma unroll
        for (int ww = 0; ww < 8; ++ww) qv += qpart[ww][t];
        qv_s[t] = qv;    // row t = sl*8 + k
    }
    __syncthreads();
    // fused final: partial over this block's 8 s-values, atomic into out
    if (t < 8) {
        float p = 0.f;
#pragma unroll
        for (int sl = 0; sl < 8; ++sl)
            p += qv_s[sl * 8 + perm_s[sl * 8 + t]];
        p *= (1.0f / 64.0f);
        atomicAdd(&out[b * 8 + t], p);
        atomicAdd(&out[4096 + b * 8 + t], p);
    }
}

extern "C" void kernel_launch(void* const* d_in, const int* in_sizes, int n_in,
                              void* d_out, int out_size, void* d_ws, size_t ws_size,
                              hipStream_t stream) {
    const float* state  = (const float*)d_in[0];
    const float* action = (const float*)d_in[1];
    const float* W1     = (const float*)d_in[2];
    const float* b1     = (const float*)d_in[3];
    const float* W2     = (const float*)d_in[4];
    const float* b2     = (const float*)d_in[5];
    const float* W3     = (const float*)d_in[6];
    const float* b3     = (const float*)d_in[7];
    const int*   perm   = (const int*)d_in[8];
    float* out = (float*)d_out;

    char* ws = (char*)d_ws;
    float*    obsW = (float*)ws;                          // 512*256*4    = 0.5 MB
    ushort_t* actW = (ushort_t*)(ws + 524288);            // 512*64*256*2 = 16 MB
    ushort_t* W2T  = (ushort_t*)(ws + 524288 + 16777216); // 128 KB

    (void)hipMemsetAsync(out, 0, (size_t)out_size * sizeof(float), stream);
    prep_kernel<<<1600, 256, 0, stream>>>(state, action, W1, b1, W2, obsW, actW, W2T);
    main_kernel<<<4096, 512, 0, stream>>>(obsW, actW, W2T, perm, b2, W3, b3, out);
}

// Round 8
// 181.774 us; speedup vs baseline: 1.0158x; 1.0147x over previous
//
#include <hip/hip_runtime.h>
#include <hip/hip_bf16.h>

typedef unsigned short ushort_t;
typedef __attribute__((ext_vector_type(8))) short short8;
typedef __attribute__((ext_vector_type(4))) float floatx4;

// B=512, S=64, N=8, D=64, A=16, H=256, IN_DIM=640

__device__ __forceinline__ float mish_f(float x) {
    float e = __expf(x);
    float w = fmaf(e, e + 2.0f, 2.0f);   // e^2x + 2e^x + 2, >= 2
    return x - 2.0f * x * __builtin_amdgcn_rcpf(w);
}

// round-half-up bf16 (ties differ from RNE by 1 ulp; threshold slack 4.6x)
__device__ __forceinline__ unsigned f2bf_u(float f) {
    return (__float_as_uint(f) + 0x8000u) >> 16;
}

__device__ __forceinline__ unsigned pk_bf2(float a, float b) {
    unsigned ua = __float_as_uint(a) + 0x8000u;
    unsigned ub = __float_as_uint(b) + 0x8000u;
    return (ua >> 16) | (ub & 0xffff0000u);
}

// sum across each 16-lane row, pure VALU (DPP), no LDS
__device__ __forceinline__ float dpp_sum16(float v) {
    int x = __float_as_int(v);
    v += __int_as_float(__builtin_amdgcn_update_dpp(0, x, 0xB1, 0xF, 0xF, true));  // quad_perm xor1
    x = __float_as_int(v);
    v += __int_as_float(__builtin_amdgcn_update_dpp(0, x, 0x4E, 0xF, 0xF, true));  // quad_perm xor2
    x = __float_as_int(v);
    v += __int_as_float(__builtin_amdgcn_update_dpp(0, x, 0x124, 0xF, 0xF, true)); // row_ror:4
    x = __float_as_int(v);
    v += __int_as_float(__builtin_amdgcn_update_dpp(0, x, 0x128, 0xF, 0xF, true)); // row_ror:8
    return v;
}

// ---------------- prep (2-dispatch pipeline: this + main) ----------------
// blocks [0,512):   per-b: obsW (split-K over 2 thread-halves) + actW (j-split)
// blocks [512,544): W2T transpose; first 16 of them also zero `out`
__global__ __launch_bounds__(512) void prep_kernel(
        const float* __restrict__ state,
        const float* __restrict__ action,
        const float* __restrict__ W1,
        const float* __restrict__ b1,
        const float* __restrict__ W2,
        float* __restrict__ obsW,
        ushort_t* __restrict__ actW,
        ushort_t* __restrict__ W2T,
        float* __restrict__ out) {
    int bid = blockIdx.x;
    int t = threadIdx.x;
    if (bid < 512) {
        int b = bid;
        __shared__ float part[2][256];
        // ---- obsW: c = t&255, f-half = t>>8 ----
        {
            int c = t & 255;
            int fh = t >> 8;
            const float* stp = state + (size_t)b * 512 + fh * 256;  // wave-uniform -> s_load
            const float* w1p = W1 + (size_t)(fh * 256) * 256 + c;
            float a0 = 0.f, a1 = 0.f, a2 = 0.f, a3 = 0.f;
#pragma unroll 8
            for (int f = 0; f < 256; f += 4) {
                a0 = fmaf(stp[f + 0], w1p[(f + 0) * 256], a0);
                a1 = fmaf(stp[f + 1], w1p[(f + 1) * 256], a1);
                a2 = fmaf(stp[f + 2], w1p[(f + 2) * 256], a2);
                a3 = fmaf(stp[f + 3], w1p[(f + 3) * 256], a3);
            }
            part[fh][c] = (a0 + a1) + (a2 + a3);
        }
        __syncthreads();
        if (t < 256) obsW[b * 256 + t] = part[0][t] + part[1][t] + b1[t];
        // ---- actW: c = t&255, j = (t>>8)*4 + 0..3 ----
        {
            int c = t & 255;
            int jh = t >> 8;
            const float* acp = action + (size_t)b * 128;   // wave-uniform -> s_load
#pragma unroll
            for (int jj = 0; jj < 4; ++jj) {
                int j = jh * 4 + jj;
                const float* W1a = W1 + (size_t)(512 + j * 16) * 256 + c;
                float acc[8];
#pragma unroll
                for (int n = 0; n < 8; ++n) acc[n] = 0.f;
#pragma unroll
                for (int a = 0; a < 16; ++a) {
                    float w = W1a[a * 256];
#pragma unroll
                    for (int n = 0; n < 8; ++n)
                        acc[n] = fmaf(acp[n * 16 + a], w, acc[n]);
                }
#pragma unroll
                for (int n = 0; n < 8; ++n)
                    actW[(((size_t)b * 8 + n) * 8 + j) * 256 + c] = (ushort_t)f2bf_u(acc[n]);
            }
        }
    } else {
        int blk = bid - 512;             // 0..31
        if (blk < 16) out[blk * 512 + t] = 0.0f;   // zero both output copies (8192 floats)
        int n = blk * 8 + (t >> 6);
        int klo = t & 63;
#pragma unroll
        for (int kk = 0; kk < 4; ++kk) {
            int k = kk * 64 + klo;
            W2T[n * 256 + k] = (ushort_t)f2bf_u(W2[k * 256 + n]);
        }
    }
}

// ---------------- main: h1 build (frag-order LDS) + layer2 MFMA + layer3 + reduce ----------------
// h1 layout: chunk (mt,ks) of 1056B (528 ushorts = 1KB data + 32B pad);
// within chunk, lane L=(q*16+lo) holds granule (ks*4+q) of row (mt*16+lo) at L*16B.
#define CHUNK_US 528   // ushorts per chunk

__global__ __launch_bounds__(512, 4) void main_kernel(
        const float* __restrict__ obsW, const ushort_t* __restrict__ actW,
        const ushort_t* __restrict__ W2T, const int* __restrict__ perm,
        const float* __restrict__ b2,
        const float* __restrict__ W3, const float* __restrict__ b3,
        float* __restrict__ out) {
    __shared__ __align__(16) ushort_t h1[32 * CHUNK_US];   // 33 KB
    __shared__ __align__(16) float obsb[256];
    __shared__ int perm_s[64];
    __shared__ float qpart[8][64];
    __shared__ float qv_s[64];

    int t = threadIdx.x;
    int bid = blockIdx.x;
    // XCD swizzle: all 8 s-group blocks of one b share blockIdx%8 -> same XCD L2
    int b = (bid & 7) * 64 + ((bid >> 3) & 63);
    int sg = bid >> 9;
    int s0 = sg * 8;

    int w = t >> 6;        // wave 0..7
    int L = t & 63;
    int lo = L & 15;
    int q = L >> 4;

    if (t < 256) obsb[t] = obsW[b * 256 + t];            // includes b1
    else if (t < 320) perm_s[t - 256] = perm[((size_t)b * 64 + s0) * 8 + (t - 256)];

    // hoist first 4 B-operand loads (independent of LDS)
    const ushort_t* w2base = W2T + ((size_t)(w * 32 + lo)) * 256 + q * 8;
    short8 bpre[4];
    bpre[0] = *reinterpret_cast<const short8*>(w2base + 0 * 16 * 256 + 0 * 32);
    bpre[1] = *reinterpret_cast<const short8*>(w2base + 1 * 16 * 256 + 0 * 32);
    bpre[2] = *reinterpret_cast<const short8*>(w2base + 0 * 16 * 256 + 1 * 32);
    bpre[3] = *reinterpret_cast<const short8*>(w2base + 1 * 16 * 256 + 1 * 32);

    __syncthreads();

    // ---- build h1: thread = (sl = wave, half-granule hg = lane); 4 cols/thread ----
    {
        int sl = w;                  // s-slot 0..7
        int hg = L;                  // half-granule 0..63 -> cols hg*4..hg*4+3
        int g = hg >> 1;
        int ks = g >> 2;
        int qq = g & 3;
        int half = hg & 1;
        const ushort_t* actg = actW + (size_t)b * 64 * 256 + hg * 4;
        uint2 av[8];
#pragma unroll
        for (int j = 0; j < 8; ++j) {
            int p = perm_s[sl * 8 + j];
            av[j] = *reinterpret_cast<const uint2*>(actg + (p * 8 + j) * 256);
        }
        float4 ob = *reinterpret_cast<const float4*>(obsb + hg * 4);
        float r0 = ob.x, r1 = ob.y, r2 = ob.z, r3 = ob.w;
        ushort_t* dst0 = h1 + (qq * 16) * 8 + half * 4 + ks * CHUNK_US;
#pragma unroll
        for (int j = 0; j < 8; ++j) {
            r0 += __uint_as_float(av[j].x << 16);
            r1 += __uint_as_float(av[j].x & 0xffff0000u);
            r2 += __uint_as_float(av[j].y << 16);
            r3 += __uint_as_float(av[j].y & 0xffff0000u);
            int row = sl * 8 + j;
            int mt = row >> 4, lr = row & 15;
            uint2 pk = make_uint2(pk_bf2(mish_f(r0), mish_f(r1)),
                                  pk_bf2(mish_f(r2), mish_f(r3)));
            *reinterpret_cast<uint2*>(dst0 + mt * 8 * CHUNK_US + lr * 8) = pk;
        }
    }
    __syncthreads();

    // ---- layer2: M=64, N=256, K=256; wave w owns 32-col N-strip ----
    floatx4 acc[4][2];
#pragma unroll
    for (int mt = 0; mt < 4; ++mt)
#pragma unroll
        for (int nt = 0; nt < 2; ++nt)
            acc[mt][nt] = (floatx4){0.f, 0.f, 0.f, 0.f};

    const ushort_t* h1b = h1 + L * 8;   // lane offset L*16B

#pragma unroll
    for (int ks = 0; ks < 8; ++ks) {
        short8 afr[4];
#pragma unroll
        for (int mt = 0; mt < 4; ++mt)
            afr[mt] = *reinterpret_cast<const short8*>(h1b + (mt * 8 + ks) * CHUNK_US);
#pragma unroll
        for (int nt = 0; nt < 2; ++nt) {
            short8 bfr;
            if (ks == 0)      bfr = bpre[nt];
            else if (ks == 1) bfr = bpre[2 + nt];
            else              bfr = *reinterpret_cast<const short8*>(w2base + nt * 16 * 256 + ks * 32);
#pragma unroll
            for (int mt = 0; mt < 4; ++mt)
                acc[mt][nt] = __builtin_amdgcn_mfma_f32_16x16x32_bf16(afr[mt], bfr, acc[mt][nt], 0, 0, 0);
        }
    }

    // ---- epilogue: h2 = mish(acc + b2), layer3 dot with W3; DPP row-reduce ----
    float b2c[2], w3c[2];
#pragma unroll
    for (int nt = 0; nt < 2; ++nt) {
        int col = w * 32 + nt * 16 + lo;
        b2c[nt] = b2[col];
        w3c[nt] = W3[col];
    }
#pragma unroll
    for (int mt = 0; mt < 4; ++mt) {
        float part[4] = {0.f, 0.f, 0.f, 0.f};
#pragma unroll
        for (int nt = 0; nt < 2; ++nt) {
#pragma unroll
            for (int r = 0; r < 4; ++r) {
                float h2 = mish_f(acc[mt][nt][r] + b2c[nt]);
                part[r] = fmaf(h2, w3c[nt], part[r]);
            }
        }
#pragma unroll
        for (int r = 0; r < 4; ++r) {
            float v = dpp_sum16(part[r]);
            if (lo == 0) qpart[w][mt * 16 + q * 4 + r] = v;
        }
    }
    __syncthreads();
    if (t < 64) {
        float qv = b3[0];
#pragma unroll
        for (int ww = 0; ww < 8; ++ww) qv += qpart[ww][t];
        qv_s[t] = qv;    // row t = sl*8 + k
    }
    __syncthreads();
    // fused final: partial over this block's 8 s-values, atomic into out
    if (t < 8) {
        float p = 0.f;
#pragma unroll
        for (int sl = 0; sl < 8; ++sl)
            p += qv_s[sl * 8 + perm_s[sl * 8 + t]];
        p *= (1.0f / 64.0f);
        atomicAdd(&out[b * 8 + t], p);
        atomicAdd(&out[4096 + b * 8 + t], p);
    }
}

extern "C" void kernel_launch(void* const* d_in, const int* in_sizes, int n_in,
                              void* d_out, int out_size, void* d_ws, size_t ws_size,
                              hipStream_t stream) {
    const float* state  = (const float*)d_in[0];
    const float* action = (const float*)d_in[1];
    const float* W1     = (const float*)d_in[2];
    const float* b1     = (const float*)d_in[3];
    const float* W2     = (const float*)d_in[4];
    const float* b2     = (const float*)d_in[5];
    const float* W3     = (const float*)d_in[6];
    const float* b3     = (const float*)d_in[7];
    const int*   perm   = (const int*)d_in[8];
    float* out = (float*)d_out;

    char* ws = (char*)d_ws;
    float*    obsW = (float*)ws;                          // 512*256*4    = 0.5 MB
    ushort_t* actW = (ushort_t*)(ws + 524288);            // 512*64*256*2 = 16 MB
    ushort_t* W2T  = (ushort_t*)(ws + 524288 + 16777216); // 128 KB

    prep_kernel<<<544, 512, 0, stream>>>(state, action, W1, b1, W2, obsW, actW, W2T, out);
    main_kernel<<<4096, 512, 0, stream>>>(obsW, actW, W2T, perm, b2, W3, b3, out);
}

// Round 10
// 178.348 us; speedup vs baseline: 1.0353x; 1.0192x over previous
//
#include <hip/hip_runtime.h>
#include <hip/hip_bf16.h>

typedef unsigned short ushort_t;
typedef _Float16 half_t;
typedef __attribute__((ext_vector_type(2))) _Float16 half2_t;
typedef __attribute__((ext_vector_type(8))) _Float16 half8_t;
typedef __attribute__((ext_vector_type(2))) float fx2;
typedef __attribute__((ext_vector_type(4))) float floatx4;

#define LOG2E 1.4426950408889634f
#define LN2   0.6931471805599453f

__device__ __forceinline__ float exp2_(float x) {
#if __has_builtin(__builtin_amdgcn_exp2f)
    return __builtin_amdgcn_exp2f(x);
#else
    return exp2f(x);
#endif
}

__device__ __forceinline__ half2_t cvt_pk_f16(float a, float b) {
    auto r = __builtin_amdgcn_cvt_pkrtz(a, b);   // __fp16 ext_vector(2)
    return __builtin_bit_cast(half2_t, r);
}

// packed mish in log2-domain: input t0 = x*log2e, output t0*tanh(softplus(x)) = mish(x)/ln2
__device__ __forceinline__ fx2 mish2(fx2 t0) {
    fx2 one = {1.0f, 1.0f};
    fx2 m2  = {-2.0f, -2.0f};
    fx2 u   = {exp2_(t0.x), exp2_(t0.y)};          // e^x
    fx2 s   = u + one;
    fx2 wv  = __builtin_elementwise_fma(s, s, one); // (e^x+1)^2+1 = e^2x+2e^x+2
    fx2 rr  = {__builtin_amdgcn_rcpf(wv.x), __builtin_amdgcn_rcpf(wv.y)};
    fx2 v   = __builtin_elementwise_fma(rr, m2, one);  // tanh(softplus) = 1-2/w
    return t0 * v;
}

// sum across each 16-lane row, pure VALU (DPP), no LDS
__device__ __forceinline__ float dpp_sum16(float v) {
    int x = __float_as_int(v);
    v += __int_as_float(__builtin_amdgcn_update_dpp(0, x, 0xB1, 0xF, 0xF, true));  // quad_perm xor1
    x = __float_as_int(v);
    v += __int_as_float(__builtin_amdgcn_update_dpp(0, x, 0x4E, 0xF, 0xF, true));  // quad_perm xor2
    x = __float_as_int(v);
    v += __int_as_float(__builtin_amdgcn_update_dpp(0, x, 0x124, 0xF, 0xF, true)); // row_ror:4
    x = __float_as_int(v);
    v += __int_as_float(__builtin_amdgcn_update_dpp(0, x, 0x128, 0xF, 0xF, true)); // row_ror:8
    return v;
}

// ---------------- prep ----------------
// blocks [0,512):      obsW[b][t] = (state[b]@W1obs + b1) * log2e   (fp32)
// blocks [512,2560):   actW f16 = (action@W1act)*log2e: idx=bid-512, j=idx&7, b0=(idx>>3)*2
// blocks [2560,2592):  W2T f16 transpose; first 16 also zero `out`
__global__ __launch_bounds__(256) void prep_kernel(
        const float* __restrict__ state,
        const float* __restrict__ action,
        const float* __restrict__ W1,
        const float* __restrict__ b1,
        const float* __restrict__ W2,
        float* __restrict__ obsW,
        half_t* __restrict__ actW,
        half_t* __restrict__ W2T,
        float* __restrict__ out) {
    int bid = blockIdx.x;
    int t = threadIdx.x;
    if (bid < 512) {
        int b = bid;
        const float* stp = state + (size_t)b * 512;   // wave-uniform -> s_load
        const float* w1p = W1 + t;
        float a0 = 0.f, a1 = 0.f, a2 = 0.f, a3 = 0.f;
#pragma unroll 8
        for (int f = 0; f < 512; f += 4) {
            a0 = fmaf(stp[f + 0], w1p[(f + 0) * 256], a0);
            a1 = fmaf(stp[f + 1], w1p[(f + 1) * 256], a1);
            a2 = fmaf(stp[f + 2], w1p[(f + 2) * 256], a2);
            a3 = fmaf(stp[f + 3], w1p[(f + 3) * 256], a3);
        }
        obsW[b * 256 + t] = ((a0 + a1) + (a2 + a3) + b1[t]) * LOG2E;
    } else if (bid < 2560) {
        int idx = bid - 512;
        int j = idx & 7;
        int b0 = (idx >> 3) * 2;
        const float* W1a = W1 + (size_t)(512 + j * 16) * 256;
        float wv[16];
#pragma unroll
        for (int a = 0; a < 16; ++a) wv[a] = W1a[a * 256 + t];
#pragma unroll
        for (int bb = 0; bb < 2; ++bb) {
            int b = b0 + bb;
            const float* acp = action + (size_t)b * 128;   // wave-uniform -> s_load
            float acc[8];
#pragma unroll
            for (int n = 0; n < 8; ++n) acc[n] = 0.f;
#pragma unroll
            for (int a = 0; a < 16; ++a) {
#pragma unroll
                for (int n = 0; n < 8; ++n)
                    acc[n] = fmaf(acp[n * 16 + a], wv[a], acc[n]);
            }
#pragma unroll
            for (int n = 0; n < 8; ++n)
                actW[(((size_t)b * 8 + n) * 8 + j) * 256 + t] = (half_t)(acc[n] * LOG2E);
        }
    } else {
        int blk = bid - 2560;             // 0..31
        if (blk < 16) {                   // zero both output copies (8192 floats)
            out[blk * 512 + t] = 0.0f;
            out[blk * 512 + 256 + t] = 0.0f;
        }
        int n = blk * 8 + (t >> 5);
        int klo = t & 31;
#pragma unroll
        for (int kk = 0; kk < 8; ++kk) {
            int k = kk * 32 + klo;
            W2T[n * 256 + k] = (half_t)W2[k * 256 + n];
        }
    }
}

// ---------------- main: h1 build (frag-order LDS) + layer2 MFMA + layer3 + reduce ----------------
// h1 layout: chunk (mt,ks) of 1056B (528 ushorts = 1KB data + 32B pad);
// within chunk, lane L=(q*16+lo) holds granule (ks*4+q) of row (mt*16+lo) at L*16B.
#define CHUNK_US 528   // ushorts per chunk

__global__ __launch_bounds__(512, 4) void main_kernel(
        const float* __restrict__ obsW, const half_t* __restrict__ actW,
        const half_t* __restrict__ W2T, const int* __restrict__ perm,
        const float* __restrict__ b2,
        const float* __restrict__ W3, const float* __restrict__ b3,
        float* __restrict__ out) {
    __shared__ __align__(16) ushort_t h1[32 * CHUNK_US];   // 33 KB
    __shared__ __align__(16) float obsb[256];
    __shared__ int perm_s[64];
    __shared__ float qpart[8][64];
    __shared__ float qv_s[64];

    int t = threadIdx.x;
    int bid = blockIdx.x;
    // XCD swizzle: all 8 s-group blocks of one b share blockIdx%8 -> same XCD L2
    int b = (bid & 7) * 64 + ((bid >> 3) & 63);
    int sg = bid >> 9;
    int s0 = sg * 8;

    int w = t >> 6;        // wave 0..7
    int L = t & 63;
    int lo = L & 15;
    int q = L >> 4;

    if (t < 256) obsb[t] = obsW[b * 256 + t];            // (x+b1)*log2e
    else if (t < 320) perm_s[t - 256] = perm[((size_t)b * 64 + s0) * 8 + (t - 256)];

    // hoist first 4 B-operand loads (independent of LDS)
    const half_t* w2base = W2T + ((size_t)(w * 32 + lo)) * 256 + q * 8;
    half8_t bpre[4];
    bpre[0] = *reinterpret_cast<const half8_t*>(w2base + 0 * 16 * 256 + 0 * 32);
    bpre[1] = *reinterpret_cast<const half8_t*>(w2base + 1 * 16 * 256 + 0 * 32);
    bpre[2] = *reinterpret_cast<const half8_t*>(w2base + 0 * 16 * 256 + 1 * 32);
    bpre[3] = *reinterpret_cast<const half8_t*>(w2base + 1 * 16 * 256 + 1 * 32);

    __syncthreads();

    // ---- build h1: thread = (sl = wave, half-granule hg = lane); 4 cols/thread ----
    {
        int sl = w;                  // s-slot 0..7
        int hg = L;                  // half-granule 0..63 -> cols hg*4..hg*4+3
        int g = hg >> 1;
        int ks = g >> 2;
        int qq = g & 3;
        int half = hg & 1;
        const half_t* actg = actW + (size_t)b * 64 * 256 + hg * 4;
        uint2 av[8];
#pragma unroll
        for (int j = 0; j < 8; ++j) {
            int p = perm_s[sl * 8 + j];
            av[j] = *reinterpret_cast<const uint2*>(actg + (p * 8 + j) * 256);
        }
        float4 ob = *reinterpret_cast<const float4*>(obsb + hg * 4);
        fx2 r01 = {ob.x, ob.y};
        fx2 r23 = {ob.z, ob.w};
        ushort_t* dst0 = h1 + (qq * 16) * 8 + half * 4 + ks * CHUNK_US;
#pragma unroll
        for (int j = 0; j < 8; ++j) {
            half2_t a0 = __builtin_bit_cast(half2_t, av[j].x);
            half2_t a1 = __builtin_bit_cast(half2_t, av[j].y);
            r01 += (fx2){(float)a0.x, (float)a0.y};
            r23 += (fx2){(float)a1.x, (float)a1.y};
            fx2 h01 = mish2(r01);
            fx2 h23 = mish2(r23);
            half2_t p0 = cvt_pk_f16(h01.x, h01.y);
            half2_t p1 = cvt_pk_f16(h23.x, h23.y);
            int row = sl * 8 + j;
            int mt = row >> 4, lr = row & 15;
            uint2 pk = make_uint2(__builtin_bit_cast(unsigned, p0),
                                  __builtin_bit_cast(unsigned, p1));
            *reinterpret_cast<uint2*>(dst0 + mt * 8 * CHUNK_US + lr * 8) = pk;
        }
    }
    __syncthreads();

    // ---- layer2: M=64, N=256, K=256; wave w owns 32-col N-strip; f16 MFMA ----
    floatx4 acc[4][2];
#pragma unroll
    for (int mt = 0; mt < 4; ++mt)
#pragma unroll
        for (int nt = 0; nt < 2; ++nt)
            acc[mt][nt] = (floatx4){0.f, 0.f, 0.f, 0.f};

    const ushort_t* h1b = h1 + L * 8;   // lane offset L*16B

#pragma unroll
    for (int ks = 0; ks < 8; ++ks) {
        half8_t afr[4];
#pragma unroll
        for (int mt = 0; mt < 4; ++mt)
            afr[mt] = *reinterpret_cast<const half8_t*>(h1b + (mt * 8 + ks) * CHUNK_US);
#pragma unroll
        for (int nt = 0; nt < 2; ++nt) {
            half8_t bfr;
            if (ks == 0)      bfr = bpre[nt];
            else if (ks == 1) bfr = bpre[2 + nt];
            else              bfr = *reinterpret_cast<const half8_t*>(w2base + nt * 16 * 256 + ks * 32);
#pragma unroll
            for (int mt = 0; mt < 4; ++mt)
                acc[mt][nt] = __builtin_amdgcn_mfma_f32_16x16x32_f16(afr[mt], bfr, acc[mt][nt], 0, 0, 0);
        }
    }

    // ---- epilogue: t2 = acc + b2*log2e is already the exp2 arg; dot via fdot2 ----
    int col0 = w * 32 + 0 * 16 + lo;
    int col1 = w * 32 + 1 * 16 + lo;
    fx2 b2p = {b2[col0] * LOG2E, b2[col1] * LOG2E};
    half2_t w3p = cvt_pk_f16(W3[col0] * LN2, W3[col1] * LN2);
#pragma unroll
    for (int mt = 0; mt < 4; ++mt) {
        float part[4];
#pragma unroll
        for (int r = 0; r < 4; ++r) {
            fx2 t2 = {acc[mt][0][r], acc[mt][1][r]};
            t2 += b2p;
            fx2 h = mish2(t2);
            half2_t hh = cvt_pk_f16(h.x, h.y);
#if __has_builtin(__builtin_amdgcn_fdot2)
            part[r] = __builtin_amdgcn_fdot2(__builtin_bit_cast(__fp16 __attribute__((ext_vector_type(2))), hh),
                                             __builtin_bit_cast(__fp16 __attribute__((ext_vector_type(2))), w3p),
                                             0.0f, false);
#else
            part[r] = (float)hh.x * (float)w3p.x + (float)hh.y * (float)w3p.y;
#endif
        }
#pragma unroll
        for (int r = 0; r < 4; ++r) {
            float v = dpp_sum16(part[r]);
            if (lo == 0) qpart[w][mt * 16 + q * 4 + r] = v;
        }
    }
    __syncthreads();
    if (t < 64) {
        float qv = b3[0];
#pragma unroll
        for (int ww = 0; ww < 8; ++ww) qv += qpart[ww][t];
        qv_s[t] = qv;    // row t = sl*8 + k
    }
    __syncthreads();
    // fused final: partial over this block's 8 s-values, atomic into out
    if (t < 8) {
        float p = 0.f;
#pragma unroll
        for (int sl = 0; sl < 8; ++sl)
            p += qv_s[sl * 8 + perm_s[sl * 8 + t]];
        p *= (1.0f / 64.0f);
        atomicAdd(&out[b * 8 + t], p);
        atomicAdd(&out[4096 + b * 8 + t], p);
    }
}

extern "C" void kernel_launch(void* const* d_in, const int* in_sizes, int n_in,
                              void* d_out, int out_size, void* d_ws, size_t ws_size,
                              hipStream_t stream) {
    const float* state  = (const float*)d_in[0];
    const float* action = (const float*)d_in[1];
    const float* W1     = (const float*)d_in[2];
    const float* b1     = (const float*)d_in[3];
    const float* W2     = (const float*)d_in[4];
    const float* b2     = (const float*)d_in[5];
    const float* W3     = (const float*)d_in[6];
    const float* b3     = (const float*)d_in[7];
    const int*   perm   = (const int*)d_in[8];
    float* out = (float*)d_out;

    char* ws = (char*)d_ws;
    float*  obsW = (float*)ws;                          // 512*256*4    = 0.5 MB
    half_t* actW = (half_t*)(ws + 524288);              // 512*64*256*2 = 16 MB
    half_t* W2T  = (half_t*)(ws + 524288 + 16777216);   // 128 KB

    prep_kernel<<<2592, 256, 0, stream>>>(state, action, W1, b1, W2, obsW, actW, W2T, out);
    main_kernel<<<4096, 512, 0, stream>>>(obsW, actW, W2T, perm, b2, W3, b3, out);
}

// Round 11
// 165.283 us; speedup vs baseline: 1.1171x; 1.0790x over previous
//
#include <hip/hip_runtime.h>

typedef unsigned short ushort_t;
typedef _Float16 half_t;
typedef __attribute__((ext_vector_type(2))) _Float16 half2_t;
typedef __attribute__((ext_vector_type(8))) _Float16 half8_t;
typedef __attribute__((ext_vector_type(2))) __fp16 fp16x2;
typedef __attribute__((ext_vector_type(2))) float fx2;
typedef __attribute__((ext_vector_type(4))) float floatx4;

#define LOG2E 1.4426950408889634f
#define LN2   0.6931471805599453f

__device__ __forceinline__ float exp2_(float x) {
#if __has_builtin(__builtin_amdgcn_exp2f)
    return __builtin_amdgcn_exp2f(x);
#else
    return exp2f(x);
#endif
}

__device__ __forceinline__ half2_t cvt_pk_f16(float a, float b) {
    auto r = __builtin_amdgcn_cvt_pkrtz(a, b);
    return __builtin_bit_cast(half2_t, r);
}

__device__ __forceinline__ float fdot2_(half2_t a, half2_t b) {
#if __has_builtin(__builtin_amdgcn_fdot2)
    return __builtin_amdgcn_fdot2(__builtin_bit_cast(fp16x2, a),
                                  __builtin_bit_cast(fp16x2, b), 0.0f, false);
#else
    return (float)a.x * (float)b.x + (float)a.y * (float)b.y;
#endif
}

// packed mish in log2-domain: input t0 = x*log2e, output = mish(x)/ln2
__device__ __forceinline__ fx2 mish2(fx2 t0) {
    fx2 one = {1.0f, 1.0f};
    fx2 m2  = {-2.0f, -2.0f};
    fx2 u   = {exp2_(t0.x), exp2_(t0.y)};
    fx2 s   = u + one;
    fx2 wv  = __builtin_elementwise_fma(s, s, one);     // e^2x+2e^x+2
    fx2 rr  = {__builtin_amdgcn_rcpf(wv.x), __builtin_amdgcn_rcpf(wv.y)};
    fx2 v   = __builtin_elementwise_fma(rr, m2, one);   // tanh(softplus)
    return t0 * v;
}

// sum across each 16-lane row, pure VALU (DPP), no LDS
__device__ __forceinline__ float dpp_sum16(float v) {
    int x = __float_as_int(v);
    v += __int_as_float(__builtin_amdgcn_update_dpp(0, x, 0xB1, 0xF, 0xF, true));
    x = __float_as_int(v);
    v += __int_as_float(__builtin_amdgcn_update_dpp(0, x, 0x4E, 0xF, 0xF, true));
    x = __float_as_int(v);
    v += __int_as_float(__builtin_amdgcn_update_dpp(0, x, 0x124, 0xF, 0xF, true));
    x = __float_as_int(v);
    v += __int_as_float(__builtin_amdgcn_update_dpp(0, x, 0x128, 0xF, 0xF, true));
    return v;
}

// ---------------- prep (unchanged from R10) ----------------
__global__ __launch_bounds__(256) void prep_kernel(
        const float* __restrict__ state,
        const float* __restrict__ action,
        const float* __restrict__ W1,
        const float* __restrict__ b1,
        const float* __restrict__ W2,
        float* __restrict__ obsW,
        half_t* __restrict__ actW,
        half_t* __restrict__ W2T,
        float* __restrict__ out) {
    int bid = blockIdx.x;
    int t = threadIdx.x;
    if (bid < 512) {
        int b = bid;
        const float* stp = state + (size_t)b * 512;
        const float* w1p = W1 + t;
        float a0 = 0.f, a1 = 0.f, a2 = 0.f, a3 = 0.f;
#pragma unroll 8
        for (int f = 0; f < 512; f += 4) {
            a0 = fmaf(stp[f + 0], w1p[(f + 0) * 256], a0);
            a1 = fmaf(stp[f + 1], w1p[(f + 1) * 256], a1);
            a2 = fmaf(stp[f + 2], w1p[(f + 2) * 256], a2);
            a3 = fmaf(stp[f + 3], w1p[(f + 3) * 256], a3);
        }
        obsW[b * 256 + t] = ((a0 + a1) + (a2 + a3) + b1[t]) * LOG2E;
    } else if (bid < 2560) {
        int idx = bid - 512;
        int j = idx & 7;
        int b0 = (idx >> 3) * 2;
        const float* W1a = W1 + (size_t)(512 + j * 16) * 256;
        float wv[16];
#pragma unroll
        for (int a = 0; a < 16; ++a) wv[a] = W1a[a * 256 + t];
#pragma unroll
        for (int bb = 0; bb < 2; ++bb) {
            int b = b0 + bb;
            const float* acp = action + (size_t)b * 128;
            float acc[8];
#pragma unroll
            for (int n = 0; n < 8; ++n) acc[n] = 0.f;
#pragma unroll
            for (int a = 0; a < 16; ++a) {
#pragma unroll
                for (int n = 0; n < 8; ++n)
                    acc[n] = fmaf(acp[n * 16 + a], wv[a], acc[n]);
            }
#pragma unroll
            for (int n = 0; n < 8; ++n)
                actW[(((size_t)b * 8 + n) * 8 + j) * 256 + t] = (half_t)(acc[n] * LOG2E);
        }
    } else {
        int blk = bid - 2560;
        if (blk < 16) {
            out[blk * 512 + t] = 0.0f;
            out[blk * 512 + 256 + t] = 0.0f;
        }
        int n = blk * 8 + (t >> 5);
        int klo = t & 31;
#pragma unroll
        for (int kk = 0; kk < 8; ++kk) {
            int k = kk * 32 + klo;
            W2T[n * 256 + k] = (half_t)W2[k * 256 + n];
        }
    }
}

// ---------------- main: two s-groups per block, software-pipelined ----------------
#define CHUNK_US 528

__global__ __launch_bounds__(512, 4) void main_kernel(
        const float* __restrict__ obsW, const half_t* __restrict__ actW,
        const half_t* __restrict__ W2T, const int* __restrict__ perm,
        const float* __restrict__ b2,
        const float* __restrict__ W3, const float* __restrict__ b3,
        float* __restrict__ out) {
    __shared__ __align__(16) ushort_t h1[2][32 * CHUNK_US];  // 66 KB
    __shared__ __align__(16) float obsb[256];
    __shared__ int perm_s[128];
    __shared__ float qpart[2][8][64];                        // 4 KB

    int t = threadIdx.x;
    int bid = blockIdx.x;
    int b = (bid & 7) * 64 + ((bid >> 3) & 63);   // XCD swizzle
    int sgp = bid >> 9;                            // 0..3
    int s0 = sgp * 16;

    int w = t >> 6;
    int L = t & 63;
    int lo = L & 15;
    int q = L >> 4;

    if (t < 256) obsb[t] = obsW[b * 256 + t];
    else if (t < 384) perm_s[t - 256] = perm[((size_t)b * 64 + s0) * 8 + (t - 256)];

    const half_t* w2base = W2T + ((size_t)(w * 32 + lo)) * 256 + q * 8;
    half8_t bpre[4];
    bpre[0] = *reinterpret_cast<const half8_t*>(w2base + 0 * 4096 + 0 * 32);
    bpre[1] = *reinterpret_cast<const half8_t*>(w2base + 1 * 4096 + 0 * 32);
    bpre[2] = *reinterpret_cast<const half8_t*>(w2base + 0 * 4096 + 1 * 32);
    bpre[3] = *reinterpret_cast<const half8_t*>(w2base + 1 * 4096 + 1 * 32);

    // build geometry: thread covers cols L*4..L*4+3 of rows (w*8+j)
    int g = L >> 1;
    int ksg = g >> 2;
    int qq = g & 3;
    int halfsel = L & 1;
    const half_t* actg = actW + (size_t)b * 64 * 256 + L * 4;
    int dstoff = qq * 128 + halfsel * 4 + ksg * CHUNK_US;

    __syncthreads();   // B0: obsb/perm_s visible

    float4 ob = *reinterpret_cast<const float4*>(obsb + L * 4);

    // ---- build half 0 ----
    {
        uint2 av[8];
#pragma unroll
        for (int j = 0; j < 8; ++j) {
            int p = perm_s[(0 * 8 + w) * 8 + j];
            av[j] = *reinterpret_cast<const uint2*>(actg + (p * 8 + j) * 256);
        }
        fx2 r01 = {ob.x, ob.y};
        fx2 r23 = {ob.z, ob.w};
        ushort_t* dst0 = h1[0] + dstoff;
#pragma unroll
        for (int j = 0; j < 8; ++j) {
            half2_t a0 = __builtin_bit_cast(half2_t, av[j].x);
            half2_t a1 = __builtin_bit_cast(half2_t, av[j].y);
            r01 += (fx2){(float)a0.x, (float)a0.y};
            r23 += (fx2){(float)a1.x, (float)a1.y};
            fx2 h01 = mish2(r01);
            fx2 h23 = mish2(r23);
            int row = w * 8 + j;
            int mt2 = row >> 4, lr = row & 15;
            uint2 pk = make_uint2(__builtin_bit_cast(unsigned, cvt_pk_f16(h01.x, h01.y)),
                                  __builtin_bit_cast(unsigned, cvt_pk_f16(h23.x, h23.y)));
            *reinterpret_cast<uint2*>(dst0 + mt2 * 8 * CHUNK_US + lr * 8) = pk;
        }
    }
    __syncthreads();   // B1: h1[0] ready

    // ---- phase 1: K-loop(half0) interleaved with build(half1) ----
    floatx4 acc0[4][2];
#pragma unroll
    for (int mt = 0; mt < 4; ++mt)
#pragma unroll
        for (int nt = 0; nt < 2; ++nt) acc0[mt][nt] = (floatx4){0.f, 0.f, 0.f, 0.f};
    {
        uint2 av[8];
#pragma unroll
        for (int j = 0; j < 8; ++j) {
            int p = perm_s[(1 * 8 + w) * 8 + j];
            av[j] = *reinterpret_cast<const uint2*>(actg + (p * 8 + j) * 256);
        }
        fx2 r01 = {ob.x, ob.y};
        fx2 r23 = {ob.z, ob.w};
        ushort_t* dst1 = h1[1] + dstoff;
        const ushort_t* h1b0 = h1[0] + L * 8;
#pragma unroll
        for (int ks = 0; ks < 8; ++ks) {
            half8_t afr[4];
#pragma unroll
            for (int mt = 0; mt < 4; ++mt)
                afr[mt] = *reinterpret_cast<const half8_t*>(h1b0 + (mt * 8 + ks) * CHUNK_US);
            half8_t bfr0 = (ks == 0) ? bpre[0] : (ks == 1) ? bpre[2]
                         : *reinterpret_cast<const half8_t*>(w2base + 0 * 4096 + ks * 32);
            half8_t bfr1 = (ks == 0) ? bpre[1] : (ks == 1) ? bpre[3]
                         : *reinterpret_cast<const half8_t*>(w2base + 1 * 4096 + ks * 32);
#pragma unroll
            for (int mt = 0; mt < 4; ++mt) {
                acc0[mt][0] = __builtin_amdgcn_mfma_f32_16x16x32_f16(afr[mt], bfr0, acc0[mt][0], 0, 0, 0);
                acc0[mt][1] = __builtin_amdgcn_mfma_f32_16x16x32_f16(afr[mt], bfr1, acc0[mt][1], 0, 0, 0);
            }
            // build1 step j=ks (VALU/trans fills MFMA shadow)
            {
                half2_t a0 = __builtin_bit_cast(half2_t, av[ks].x);
                half2_t a1 = __builtin_bit_cast(half2_t, av[ks].y);
                r01 += (fx2){(float)a0.x, (float)a0.y};
                r23 += (fx2){(float)a1.x, (float)a1.y};
                fx2 h01 = mish2(r01);
                fx2 h23 = mish2(r23);
                int row = w * 8 + ks;
                int mt2 = row >> 4, lr = row & 15;
                uint2 pk = make_uint2(__builtin_bit_cast(unsigned, cvt_pk_f16(h01.x, h01.y)),
                                      __builtin_bit_cast(unsigned, cvt_pk_f16(h23.x, h23.y)));
                *reinterpret_cast<uint2*>(dst1 + mt2 * 8 * CHUNK_US + lr * 8) = pk;
            }
        }
    }
    __syncthreads();   // B2: h1[1] ready, h1[0] consumed

    // ---- phase 2: K-loop(half1) interleaved with epilogue(half0) ----
    int col0 = w * 32 + 0 * 16 + lo;
    int col1 = w * 32 + 1 * 16 + lo;
    fx2 b2p = {b2[col0] * LOG2E, b2[col1] * LOG2E};
    half2_t w3p = cvt_pk_f16(W3[col0] * LN2, W3[col1] * LN2);

    floatx4 acc1[4][2];
#pragma unroll
    for (int mt = 0; mt < 4; ++mt)
#pragma unroll
        for (int nt = 0; nt < 2; ++nt) acc1[mt][nt] = (floatx4){0.f, 0.f, 0.f, 0.f};
    {
        const ushort_t* h1b1 = h1[1] + L * 8;
#pragma unroll
        for (int ks = 0; ks < 8; ++ks) {
            half8_t afr[4];
#pragma unroll
            for (int mt = 0; mt < 4; ++mt)
                afr[mt] = *reinterpret_cast<const half8_t*>(h1b1 + (mt * 8 + ks) * CHUNK_US);
            half8_t bfr0 = (ks == 0) ? bpre[0] : (ks == 1) ? bpre[2]
                         : *reinterpret_cast<const half8_t*>(w2base + 0 * 4096 + ks * 32);
            half8_t bfr1 = (ks == 0) ? bpre[1] : (ks == 1) ? bpre[3]
                         : *reinterpret_cast<const half8_t*>(w2base + 1 * 4096 + ks * 32);
#pragma unroll
            for (int mt = 0; mt < 4; ++mt) {
                acc1[mt][0] = __builtin_amdgcn_mfma_f32_16x16x32_f16(afr[mt], bfr0, acc1[mt][0], 0, 0, 0);
                acc1[mt][1] = __builtin_amdgcn_mfma_f32_16x16x32_f16(afr[mt], bfr1, acc1[mt][1], 0, 0, 0);
            }
            // epilogue(half0): 2 of 16 (mt,r) values per ks
#pragma unroll
            for (int v = 0; v < 2; ++v) {
                int idx = ks * 2 + v;
                int mt = idx >> 2, r = idx & 3;
                fx2 t2 = {acc0[mt][0][r], acc0[mt][1][r]};
                t2 += b2p;
                fx2 hh = mish2(t2);
                float part = fdot2_(cvt_pk_f16(hh.x, hh.y), w3p);
                float s = dpp_sum16(part);
                if (lo == 0) qpart[0][w][mt * 16 + q * 4 + r] = s;
            }
        }
    }
    // ---- epilogue(half1): wave-local (acc1 in regs), no barrier needed ----
#pragma unroll
    for (int idx = 0; idx < 16; ++idx) {
        int mt = idx >> 2, r = idx & 3;
        fx2 t2 = {acc1[mt][0][r], acc1[mt][1][r]};
        t2 += b2p;
        fx2 hh = mish2(t2);
        float part = fdot2_(cvt_pk_f16(hh.x, hh.y), w3p);
        float s = dpp_sum16(part);
        if (lo == 0) qpart[1][w][mt * 16 + q * 4 + r] = s;
    }
    __syncthreads();   // B3: all qpart visible

    // ---- final: reduce 8 waves, perm-gather, atomic ----
    if (t < 16) {
        int h = t >> 3, i = t & 7;
        float p = 0.f;
#pragma unroll
        for (int sl = 0; sl < 8; ++sl) {
            int k = perm_s[(h * 8 + sl) * 8 + i];
            int row = sl * 8 + k;
            float qv = b3[0];
#pragma unroll
            for (int ww = 0; ww < 8; ++ww) qv += qpart[h][ww][row];
            p += qv;
        }
        p *= (1.0f / 64.0f);
        atomicAdd(&out[b * 8 + i], p);
        atomicAdd(&out[4096 + b * 8 + i], p);
    }
}

extern "C" void kernel_launch(void* const* d_in, const int* in_sizes, int n_in,
                              void* d_out, int out_size, void* d_ws, size_t ws_size,
                              hipStream_t stream) {
    const float* state  = (const float*)d_in[0];
    const float* action = (const float*)d_in[1];
    const float* W1     = (const float*)d_in[2];
    const float* b1     = (const float*)d_in[3];
    const float* W2     = (const float*)d_in[4];
    const float* b2     = (const float*)d_in[5];
    const float* W3     = (const float*)d_in[6];
    const float* b3     = (const float*)d_in[7];
    const int*   perm   = (const int*)d_in[8];
    float* out = (float*)d_out;

    char* ws = (char*)d_ws;
    float*  obsW = (float*)ws;                          // 0.5 MB
    half_t* actW = (half_t*)(ws + 524288);              // 16 MB
    half_t* W2T  = (half_t*)(ws + 524288 + 16777216);   // 128 KB

    prep_kernel<<<2592, 256, 0, stream>>>(state, action, W1, b1, W2, obsW, actW, W2T, out);
    main_kernel<<<2048, 512, 0, stream>>>(obsW, actW, W2T, perm, b2, W3, b3, out);
}